// Round 1
// baseline (49.806 us; speedup 1.0000x reference)
//
#include <hip/hip_runtime.h>
#include <hip/hip_bf16.h>

#define NSEG 196
#define C_OUT 56
#define B_IMG 32
#define HW (224 * 224)

// ws layout: [B][NSEG][4] floats : {sum_c0, sum_c1, sum_c2, count}

__global__ void __launch_bounds__(256) spm_accum_kernel(
    const float* __restrict__ X,      // (B, 3, H, W)
    const int* __restrict__ seg,      // (B, H, W)
    float* __restrict__ ws)           // (B, NSEG, 4)
{
    __shared__ float acc[NSEG * 4];
    const int tid = threadIdx.x;
    for (int i = tid; i < NSEG * 4; i += blockDim.x) acc[i] = 0.0f;
    __syncthreads();

    const int b = blockIdx.x;
    const float* Xb = X + (size_t)b * 3 * HW;
    const int* segb = seg + (size_t)b * HW;

    const float4* x0p = (const float4*)(Xb);
    const float4* x1p = (const float4*)(Xb + HW);
    const float4* x2p = (const float4*)(Xb + 2 * HW);
    const int4* sp = (const int4*)(segb);

    const int nvec = HW / 4;  // 12544, exact
    const int stride = gridDim.y * blockDim.x;
    for (int v = blockIdx.y * blockDim.x + tid; v < nvec; v += stride) {
        int4 s4 = sp[v];
        float4 x0 = x0p[v];
        float4 x1 = x1p[v];
        float4 x2 = x2p[v];

        atomicAdd(&acc[s4.x * 4 + 0], x0.x);
        atomicAdd(&acc[s4.x * 4 + 1], x1.x);
        atomicAdd(&acc[s4.x * 4 + 2], x2.x);
        atomicAdd(&acc[s4.x * 4 + 3], 1.0f);

        atomicAdd(&acc[s4.y * 4 + 0], x0.y);
        atomicAdd(&acc[s4.y * 4 + 1], x1.y);
        atomicAdd(&acc[s4.y * 4 + 2], x1.y * 0.0f + x2.y);  // keep simple: see below
        atomicAdd(&acc[s4.y * 4 + 3], 1.0f);

        atomicAdd(&acc[s4.z * 4 + 0], x0.z);
        atomicAdd(&acc[s4.z * 4 + 1], x1.z);
        atomicAdd(&acc[s4.z * 4 + 2], x2.z);
        atomicAdd(&acc[s4.z * 4 + 3], 1.0f);

        atomicAdd(&acc[s4.w * 4 + 0], x0.w);
        atomicAdd(&acc[s4.w * 4 + 1], x1.w);
        atomicAdd(&acc[s4.w * 4 + 2], x2.w);
        atomicAdd(&acc[s4.w * 4 + 3], 1.0f);
    }
    __syncthreads();

    float* wsb = ws + (size_t)b * NSEG * 4;
    for (int i = tid; i < NSEG * 4; i += blockDim.x) {
        atomicAdd(&wsb[i], acc[i]);
    }
}

__global__ void __launch_bounds__(256) spm_project_kernel(
    const float* __restrict__ ws,     // (B, NSEG, 4)
    const float* __restrict__ Wm,     // (C_OUT, 3)
    const float* __restrict__ bias,   // (C_OUT)
    float* __restrict__ out)          // (B, NSEG, C_OUT)
{
    const int total = B_IMG * NSEG * C_OUT;
    int idx = blockIdx.x * blockDim.x + threadIdx.x;
    if (idx >= total) return;

    int o = idx % C_OUT;
    int bs = idx / C_OUT;

    const float* a = ws + (size_t)bs * 4;
    float s0 = a[0], s1 = a[1], s2 = a[2], cnt = a[3];
    float inv = 1.0f / fmaxf(cnt, 1.0f);

    float r = (Wm[o * 3 + 0] * s0 + Wm[o * 3 + 1] * s1 + Wm[o * 3 + 2] * s2) * inv
              + bias[o];
    out[idx] = r;
}

extern "C" void kernel_launch(void* const* d_in, const int* in_sizes, int n_in,
                              void* d_out, int out_size, void* d_ws, size_t ws_size,
                              hipStream_t stream) {
    const float* X = (const float*)d_in[0];
    const int* seg = (const int*)d_in[1];
    const float* Wm = (const float*)d_in[2];
    const float* bias = (const float*)d_in[3];
    float* out = (float*)d_out;
    float* ws = (float*)d_ws;

    const size_t ws_bytes = (size_t)B_IMG * NSEG * 4 * sizeof(float);
    hipMemsetAsync(ws, 0, ws_bytes, stream);

    dim3 grid1(B_IMG, 16);
    spm_accum_kernel<<<grid1, 256, 0, stream>>>(X, seg, ws);

    const int total = B_IMG * NSEG * C_OUT;
    int blocks2 = (total + 255) / 256;
    spm_project_kernel<<<blocks2, 256, 0, stream>>>(ws, Wm, bias, out);
}

// Round 2
// 47.265 us; speedup vs baseline: 1.0538x; 1.0538x over previous
//
#include <hip/hip_runtime.h>
#include <hip/hip_bf16.h>

#define NSEG 196
#define C_OUT 56
#define B_IMG 32
#define HW (224 * 224)
#define NCHUNK 16
#define NVEC (HW / 4)          // 12544 float4 per channel plane
#define VPC (NVEC / NCHUNK)    // 784 vec4 per chunk (exact)

// ws layout: [B][NCHUNK][NSEG*4] floats : per-block partial {s0,s1,s2,count}
// Every slot is written unconditionally by kernel 1 -> no zero-init needed.

__global__ void __launch_bounds__(256) spm_accum_kernel(
    const float* __restrict__ X,      // (B, 3, H, W)
    const int* __restrict__ seg,      // (B, H, W)
    float* __restrict__ partial)      // (B, NCHUNK, NSEG*4)
{
    __shared__ float acc[NSEG * 4];
    const int tid = threadIdx.x;
    for (int i = tid; i < NSEG * 4; i += 256) acc[i] = 0.0f;
    __syncthreads();

    const int b = blockIdx.x;
    const int chunk = blockIdx.y;
    const float* Xb = X + (size_t)b * 3 * HW;
    const int* segb = seg + (size_t)b * HW;

    const float4* x0p = (const float4*)(Xb);
    const float4* x1p = (const float4*)(Xb + HW);
    const float4* x2p = (const float4*)(Xb + 2 * HW);
    const int4* sp = (const int4*)(segb);

    const int vend = (chunk + 1) * VPC;
    for (int v = chunk * VPC + tid; v < vend; v += 256) {
        int4 s4 = sp[v];
        float4 x0 = x0p[v];
        float4 x1 = x1p[v];
        float4 x2 = x2p[v];

        atomicAdd(&acc[s4.x * 4 + 0], x0.x);
        atomicAdd(&acc[s4.x * 4 + 1], x1.x);
        atomicAdd(&acc[s4.x * 4 + 2], x2.x);
        atomicAdd(&acc[s4.x * 4 + 3], 1.0f);

        atomicAdd(&acc[s4.y * 4 + 0], x0.y);
        atomicAdd(&acc[s4.y * 4 + 1], x1.y);
        atomicAdd(&acc[s4.y * 4 + 2], x2.y);
        atomicAdd(&acc[s4.y * 4 + 3], 1.0f);

        atomicAdd(&acc[s4.z * 4 + 0], x0.z);
        atomicAdd(&acc[s4.z * 4 + 1], x1.z);
        atomicAdd(&acc[s4.z * 4 + 2], x2.z);
        atomicAdd(&acc[s4.z * 4 + 3], 1.0f);

        atomicAdd(&acc[s4.w * 4 + 0], x0.w);
        atomicAdd(&acc[s4.w * 4 + 1], x1.w);
        atomicAdd(&acc[s4.w * 4 + 2], x2.w);
        atomicAdd(&acc[s4.w * 4 + 3], 1.0f);
    }
    __syncthreads();

    float* dst = partial + ((size_t)b * NCHUNK + chunk) * (NSEG * 4);
    for (int i = tid; i < NSEG * 4; i += 256) dst[i] = acc[i];
}

__global__ void __launch_bounds__(256) spm_finalize_kernel(
    const float* __restrict__ partial, // (B, NCHUNK, NSEG*4)
    const float* __restrict__ Wm,      // (C_OUT, 3)
    const float* __restrict__ bias,    // (C_OUT)
    float* __restrict__ out)           // (B, NSEG, C_OUT)
{
    __shared__ float acc[NSEG * 4];
    __shared__ float Ws[C_OUT * 3];
    __shared__ float bs[C_OUT];

    const int tid = threadIdx.x;
    const int b = blockIdx.x;

    if (tid < C_OUT * 3) Ws[tid] = Wm[tid];
    if (tid < C_OUT) bs[tid] = bias[tid];

    const float* src = partial + (size_t)b * NCHUNK * (NSEG * 4);
    for (int i = tid; i < NSEG * 4; i += 256) {
        float s = 0.0f;
        #pragma unroll
        for (int c = 0; c < NCHUNK; ++c) s += src[c * (NSEG * 4) + i];
        acc[i] = s;
    }
    __syncthreads();

    float* outb = out + (size_t)b * NSEG * C_OUT;
    for (int idx = tid; idx < NSEG * C_OUT; idx += 256) {
        int sg = idx / C_OUT;
        int o = idx - sg * C_OUT;
        float s0 = acc[sg * 4 + 0];
        float s1 = acc[sg * 4 + 1];
        float s2 = acc[sg * 4 + 2];
        float cnt = acc[sg * 4 + 3];
        float inv = 1.0f / fmaxf(cnt, 1.0f);
        outb[idx] = (Ws[o * 3 + 0] * s0 + Ws[o * 3 + 1] * s1 + Ws[o * 3 + 2] * s2) * inv
                    + bs[o];
    }
}

extern "C" void kernel_launch(void* const* d_in, const int* in_sizes, int n_in,
                              void* d_out, int out_size, void* d_ws, size_t ws_size,
                              hipStream_t stream) {
    const float* X = (const float*)d_in[0];
    const int* seg = (const int*)d_in[1];
    const float* Wm = (const float*)d_in[2];
    const float* bias = (const float*)d_in[3];
    float* out = (float*)d_out;
    float* ws = (float*)d_ws;

    dim3 grid1(B_IMG, NCHUNK);
    spm_accum_kernel<<<grid1, 256, 0, stream>>>(X, seg, ws);
    spm_finalize_kernel<<<B_IMG, 256, 0, stream>>>(ws, Wm, bias, out);
}